// Round 5
// baseline (262.356 us; speedup 1.0000x reference)
//
#include <hip/hip_runtime.h>
#include <hip/hip_bf16.h>
#include <math.h>

#define D_MODEL 1024
#define N_HEADS 16
#define D_HEAD 64
#define S_ 2048

typedef __attribute__((ext_vector_type(8))) short short8;
typedef __attribute__((ext_vector_type(4))) float f32x4;
typedef __attribute__((ext_vector_type(16))) float f32x16;

static __device__ inline short f2bf(float f) {
    union { __hip_bfloat16 h; short s; } u;
    u.h = __float2bfloat16(f);
    return u.s;
}

static __device__ inline f32x4 mfma16(short8 a, short8 b, f32x4 c) {
    return __builtin_amdgcn_mfma_f32_16x16x32_bf16(a, b, c, 0, 0, 0);
}
static __device__ inline f32x16 mfma32(short8 a, short8 b, f32x16 c) {
    return __builtin_amdgcn_mfma_f32_32x32x16_bf16(a, b, c, 0, 0, 0);
}
static __device__ inline f32x16 zero16() {
    f32x16 z;
#pragma unroll
    for (int i = 0; i < 16; i++) z[i] = 0.f;
    return z;
}

static __device__ inline void load_lds16(const void* g, void* l) {
    __builtin_amdgcn_global_load_lds(
        (const __attribute__((address_space(1))) unsigned int*)g,
        (__attribute__((address_space(3))) unsigned int*)l, 16, 0, 0);
}

// ---------------- fp32 -> bf16 preconversion (inputs + weights) ----------------
__global__ __launch_bounds__(256)
void cvt_all(const float* __restrict__ q, const float* __restrict__ k,
             const float* __restrict__ v, const float* __restrict__ wq,
             const float* __restrict__ wk, const float* __restrict__ wv,
             const float* __restrict__ wo,
             short* dq, short* dk, short* dv, short* dwq, short* dwk,
             short* dwv, short* dwo) {
    size_t c = (size_t)blockIdx.x * 256 + threadIdx.x;   // 8-elem chunk id
    const float* s; short* d; size_t off;
    if (c < 524288)        { s = q;  d = dq;  off = c; }
    else if (c < 1048576)  { s = k;  d = dk;  off = c - 524288; }
    else if (c < 1572864)  { s = v;  d = dv;  off = c - 1048576; }
    else if (c < 1703936)  { s = wq; d = dwq; off = c - 1572864; }
    else if (c < 1712128)  { s = wk; d = dwk; off = c - 1703936; }
    else if (c < 1720320)  { s = wv; d = dwv; off = c - 1712128; }
    else                   { s = wo; d = dwo; off = c - 1720320; }
    const f32x4* sp = (const f32x4*)(s + off * 8);
    f32x4 a = sp[0], b = sp[1];
    short8 o;
    o[0] = f2bf(a[0]); o[1] = f2bf(a[1]); o[2] = f2bf(a[2]); o[3] = f2bf(a[3]);
    o[4] = f2bf(b[0]); o[5] = f2bf(b[1]); o[6] = f2bf(b[2]); o[7] = f2bf(b[3]);
    *(short8*)(d + off * 8) = o;
}

// ---------------- bf16 MFMA GEMM: C = (A @ W^T + bias) * scale ----------------
template<int BM, int BN, int OUT_MODE>
__device__ __forceinline__ void gemm_body(
    const short* __restrict__ A, const short* __restrict__ Wb,
    const float* __restrict__ bias, void* __restrict__ Cv,
    int bx, int by, int M, int N, int K, float out_scale, char* lds)
{
    constexpr int NI = BM / 32, NJ = BN / 32;
    constexpr int AISS = BM / 32, WISS = BN / 32;
    char* As = lds;                       // [2][BM*128]
    char* Ws = lds + 2 * BM * 128;        // [2][BN*128]
    const int t = threadIdx.x, lane = t & 63, w = t >> 6;
    const int wr = w >> 1, wc = w & 1, r15 = lane & 15, g = lane >> 4;
    const int m0 = by * BM, n0 = bx * BN;
    const size_t Kb2 = (size_t)K * 2;

    int aR[AISS], aC[AISS];
#pragma unroll
    for (int i = 0; i < AISS; i++) {
        int l = i * 4096 + t * 16;
        aR[i] = l >> 7;
        aC[i] = (l & 127) ^ (((l >> 7) & 7) << 4);
    }

    f32x4 acc[NI][NJ];
#pragma unroll
    for (int i = 0; i < NI; i++)
#pragma unroll
        for (int j = 0; j < NJ; j++) acc[i][j] = (f32x4){0.f, 0.f, 0.f, 0.f};

    const int nk = K / 64;
    auto stage = [&](int kt, int buf) {
        size_t kb = (size_t)kt * 128;
#pragma unroll
        for (int i = 0; i < AISS; i++)
            load_lds16((const char*)A + (size_t)(m0 + aR[i]) * Kb2 + kb + aC[i],
                       As + buf * (BM * 128) + i * 4096 + (w << 10));
#pragma unroll
        for (int i = 0; i < WISS; i++)
            load_lds16((const char*)Wb + (size_t)(n0 + aR[i]) * Kb2 + kb + aC[i],
                       Ws + buf * (BN * 128) + i * 4096 + (w << 10));
    };

    stage(0, 0);
    __syncthreads();
    int cur = 0;
    for (int kt = 0; kt < nk; kt++) {
        if (kt + 1 < nk) stage(kt + 1, cur ^ 1);
        const char* Ab = As + cur * (BM * 128);
        const char* Wbs = Ws + cur * (BN * 128);
#pragma unroll
        for (int kc = 0; kc < 2; kc++) {
            short8 af[NI], bw[NJ];
#pragma unroll
            for (int i = 0; i < NI; i++) {
                int r = wr * (16 * NI) + i * 16 + r15;
                af[i] = *(const short8*)(Ab + r * 128 + ((kc * 64 + g * 16) ^ ((r & 7) << 4)));
            }
#pragma unroll
            for (int j = 0; j < NJ; j++) {
                int r = wc * (16 * NJ) + j * 16 + r15;
                bw[j] = *(const short8*)(Wbs + r * 128 + ((kc * 64 + g * 16) ^ ((r & 7) << 4)));
            }
#pragma unroll
            for (int i = 0; i < NI; i++)
#pragma unroll
                for (int j = 0; j < NJ; j++)
                    acc[i][j] = mfma16(af[i], bw[j], acc[i][j]);
        }
        __syncthreads();
        cur ^= 1;
    }

#pragma unroll
    for (int i = 0; i < NI; i++) {
#pragma unroll
        for (int j = 0; j < NJ; j++) {
            int ncol = n0 + wc * (16 * NJ) + j * 16 + r15;
            float bv = bias[ncol];
#pragma unroll
            for (int reg = 0; reg < 4; reg++) {
                int mrow = m0 + wr * (16 * NI) + i * 16 + g * 4 + reg;
                float val = (acc[i][j][reg] + bv) * out_scale;
                if (OUT_MODE == 0) {
                    __builtin_nontemporal_store(val, (float*)Cv + (size_t)mrow * N + ncol);
                } else if (OUT_MODE == 1) {
                    ((short*)Cv)[(size_t)mrow * N + ncol] = f2bf(val);
                } else {
                    ((short*)Cv)[((((size_t)(mrow >> 11)) * 64 + ncol) << 11) +
                                 (mrow & 2047)] = f2bf(val);
                }
            }
        }
    }
}

__global__ __launch_bounds__(256)
void qkv_proj(const short* __restrict__ qin, const short* __restrict__ kin,
              const short* __restrict__ vin, const short* __restrict__ wqb,
              const short* __restrict__ wkb, const short* __restrict__ wvb,
              const float* __restrict__ bq, const float* __restrict__ bk,
              const float* __restrict__ bv,
              short* Qb, short* Kb, short* Vtb) {
    __shared__ char lds[65536];
    int bid = blockIdx.x;
    if (bid < 256)
        gemm_body<128, 128, 1>(qin, wqb, bq, Qb, bid & 7, bid >> 3,
                               4096, 1024, 1024, 0.18033688011112f, lds); // (1/8)*log2(e)
    else if (bid < 288)
        gemm_body<128, 64, 1>(kin, wkb, bk, Kb, 0, bid - 256,
                              4096, 64, 1024, 1.0f, lds);
    else
        gemm_body<128, 64, 2>(vin, wvb, bv, Vtb, 0, bid - 288,
                              4096, 64, 1024, 1.0f, lds);
}

__global__ __launch_bounds__(256)
void o_proj(const short* __restrict__ ctxb, const short* __restrict__ wob,
            const float* __restrict__ bo, float* __restrict__ out) {
    __shared__ char lds[65536];
    gemm_body<128, 128, 0>(ctxb, wob, bo, out, blockIdx.x & 7, blockIdx.x >> 3,
                           4096, 1024, 1024, 1.0f, lds);
}

// ---------------- Fused MQA attention v4: barrier-free, direct L1/L2 K/V ----------------
// Block = (b, h, 128-q tile), 4 waves x 32 q-rows. Q pre-scaled by log2e/8, exp2.
// K-tile (8KB) and V-tile (8KB) are L1-resident: read fragments directly from
// global. No __syncthreads anywhere; only same-wave Ps LDS round-trip for PV.
__global__ __launch_bounds__(256)
void mqa_attn4(const short* __restrict__ Qb,   // [B*S][1024] bf16 (pre-scaled)
               const short* __restrict__ Kb,   // [B*S][64]  bf16
               const short* __restrict__ Vtb,  // [B][64][S] bf16
               float* __restrict__ attn,       // [B][H][S][S] fp32
               short* __restrict__ ctxb)       // [B*S][1024] bf16
{
    __shared__ short Ps[128 * 64];

    const int t = threadIdx.x, lane = t & 63, w = t >> 6;
    const int l31 = lane & 31, h5 = lane >> 5;
    const int bid = blockIdx.x;
    const int qt = bid & 15, h = (bid >> 4) & 15, b = bid >> 8;
    const int q0 = qt * 128;
    const int wq = w * 32;

    // Q A-fragments (32x32x16: lane row = l31, k = kc*16 + h5*8 + j)
    short8 aq[4];
    {
        const char* qbase = (const char*)(Qb +
            (size_t)(b * S_ + q0 + wq + l31) * D_MODEL + h * 64);
#pragma unroll
        for (int kc = 0; kc < 4; kc++)
            aq[kc] = *(const short8*)(qbase + kc * 32 + h5 * 16);
    }

    // Per-lane K/V fragment base pointers.
    // K frag (half, kc) at tile kti: kp + kti*4096 + half*2048 + kc*16   (elements)
    const short* kp = Kb + ((size_t)b * S_ + l31) * D_HEAD + h5 * 8;
    // V frag (half, kc) at tile kti: vp + half*65536 + kti*64 + kc*16
    const short* vp = Vtb + ((size_t)b * 64 + l31) * S_ + h5 * 8;

#define KF(kti, half, kc) (*(const short8*)(kp + (kti) * 4096 + (half) * 2048 + (kc) * 16))
#define VF(kti, half, kc) (*(const short8*)(vp + (half) * 65536 + (kti) * 64 + (kc) * 16))
#define RD(base, r, cb) (*(const short8*)((const char*)(base) + (r) * 128 + ((cb) ^ (((r) & 7) << 4))))

    // ---- Pass 1: row sums of exp2(s) ----
    float lsum[16];
#pragma unroll
    for (int reg = 0; reg < 16; reg++) lsum[reg] = 0.f;

    for (int kti = 0; kti < 32; kti++) {
        f32x16 s0 = zero16(), s1 = zero16();
#pragma unroll
        for (int kc = 0; kc < 4; kc++) {
            s0 = mfma32(aq[kc], KF(kti, 0, kc), s0);
            s1 = mfma32(aq[kc], KF(kti, 1, kc), s1);
        }
#pragma unroll
        for (int reg = 0; reg < 16; reg++)
            lsum[reg] += exp2f(s0[reg]) + exp2f(s1[reg]);
    }

    float inv[16];
#pragma unroll
    for (int reg = 0; reg < 16; reg++) {
        float v = lsum[reg];
        v += __shfl_xor(v, 1); v += __shfl_xor(v, 2);
        v += __shfl_xor(v, 4); v += __shfl_xor(v, 8); v += __shfl_xor(v, 16);
        inv[reg] = 1.f / v;
    }

    // ---- Pass 2: recompute, nt-store attn, accumulate PV ----
    f32x16 ctxA = zero16(), ctxB = zero16();
    float* attn_base = attn +
        (((size_t)((b * 16 + h) * 2048 + q0 + wq + 4 * h5)) << 11) + l31;

    for (int kti = 0; kti < 32; kti++) {
        f32x16 s0 = zero16(), s1 = zero16();
#pragma unroll
        for (int kc = 0; kc < 4; kc++) {
            s0 = mfma32(aq[kc], KF(kti, 0, kc), s0);
            s1 = mfma32(aq[kc], KF(kti, 1, kc), s1);
        }
        float* arowptr = attn_base + (size_t)kti * 64;
#pragma unroll
        for (int reg = 0; reg < 16; reg++) {
            const int rloc = (reg & 3) + 8 * (reg >> 2);
            const int rps = wq + rloc + 4 * h5;
            float p0 = exp2f(s0[reg]) * inv[reg];
            __builtin_nontemporal_store(p0, arowptr + ((size_t)rloc << 11));
            *(short*)((char*)Ps + rps * 128 + ((l31 * 2) ^ ((rps & 7) << 4))) = f2bf(p0);
            float p1 = exp2f(s1[reg]) * inv[reg];
            __builtin_nontemporal_store(p1, arowptr + ((size_t)rloc << 11) + 32);
            *(short*)((char*)Ps + rps * 128 + ((64 + l31 * 2) ^ ((rps & 7) << 4))) = f2bf(p1);
        }
        // PV (same-wave DS order: Ps rows wq..wq+31 written above by this wave)
        short8 ap[4];
#pragma unroll
        for (int kc = 0; kc < 4; kc++)
            ap[kc] = RD(Ps, wq + l31, kc * 32 + h5 * 16);
#pragma unroll
        for (int kc = 0; kc < 4; kc++) {
            ctxA = mfma32(ap[kc], VF(kti, 0, kc), ctxA);
            ctxB = mfma32(ap[kc], VF(kti, 1, kc), ctxB);
        }
    }

    const int tokbase = b * 2048 + q0 + wq + 4 * h5;
#pragma unroll
    for (int reg = 0; reg < 16; reg++) {
        const int rloc = (reg & 3) + 8 * (reg >> 2);
        size_t base = (size_t)(tokbase + rloc) * D_MODEL + h * 64 + l31;
        ctxb[base]      = f2bf(ctxA[reg]);
        ctxb[base + 32] = f2bf(ctxB[reg]);
    }
#undef KF
#undef VF
#undef RD
}

extern "C" void kernel_launch(void* const* d_in, const int* in_sizes, int n_in,
                              void* d_out, int out_size, void* d_ws, size_t ws_size,
                              hipStream_t stream) {
    const float* query = (const float*)d_in[0];
    const float* key   = (const float*)d_in[1];
    const float* value = (const float*)d_in[2];
    const float* Wq_w  = (const float*)d_in[3];
    const float* Wq_b  = (const float*)d_in[4];
    const float* Wk_w  = (const float*)d_in[5];
    const float* Wk_b  = (const float*)d_in[6];
    const float* Wv_w  = (const float*)d_in[7];
    const float* Wv_b  = (const float*)d_in[8];
    const float* Wo_w  = (const float*)d_in[9];
    const float* Wo_b  = (const float*)d_in[10];

    short* ws   = (short*)d_ws;
    short* qin  = ws;
    short* kin  = qin  + (size_t)4194304;
    short* vin  = kin  + (size_t)4194304;
    short* wqb  = vin  + (size_t)4194304;
    short* wkb  = wqb  + (size_t)1048576;
    short* wvb  = wkb  + (size_t)65536;
    short* wob  = wvb  + (size_t)65536;
    short* Qb   = wob  + (size_t)1048576;
    short* Kb   = Qb   + (size_t)4194304;
    short* Vtb  = Kb   + (size_t)262144;
    short* ctxb = Vtb  + (size_t)262144;

    float* out  = (float*)d_out;
    float* attn = out + (size_t)4096 * 1024;

    dim3 blk(256);

    cvt_all<<<dim3(7232), blk, 0, stream>>>(query, key, value, Wq_w, Wk_w, Wv_w,
                                            Wo_w, qin, kin, vin, wqb, wkb, wvb, wob);
    qkv_proj<<<dim3(320), blk, 0, stream>>>(qin, kin, vin, wqb, wkb, wvb,
                                            Wq_b, Wk_b, Wv_b, Qb, Kb, Vtb);
    mqa_attn4<<<dim3(512), blk, 0, stream>>>(Qb, Kb, Vtb, attn, ctxb);
    o_proj<<<dim3(256), blk, 0, stream>>>(ctxb, wob, Wo_b, out);
}

// Round 6
// 217.790 us; speedup vs baseline: 1.2046x; 1.2046x over previous
//
#include <hip/hip_runtime.h>
#include <hip/hip_bf16.h>
#include <math.h>

#define D_MODEL 1024
#define N_HEADS 16
#define D_HEAD 64
#define S_ 2048

typedef __attribute__((ext_vector_type(8))) short short8;
typedef __attribute__((ext_vector_type(4))) float f32x4;
typedef __attribute__((ext_vector_type(16))) float f32x16;

static __device__ inline short f2bf(float f) {
    union { __hip_bfloat16 h; short s; } u;
    u.h = __float2bfloat16(f);
    return u.s;
}

static __device__ inline f32x4 mfma16(short8 a, short8 b, f32x4 c) {
    return __builtin_amdgcn_mfma_f32_16x16x32_bf16(a, b, c, 0, 0, 0);
}
static __device__ inline f32x16 mfma32(short8 a, short8 b, f32x16 c) {
    return __builtin_amdgcn_mfma_f32_32x32x16_bf16(a, b, c, 0, 0, 0);
}
static __device__ inline f32x16 zero16() {
    f32x16 z;
#pragma unroll
    for (int i = 0; i < 16; i++) z[i] = 0.f;
    return z;
}

static __device__ inline void load_lds16(const void* g, void* l) {
    __builtin_amdgcn_global_load_lds(
        (const __attribute__((address_space(1))) unsigned int*)g,
        (__attribute__((address_space(3))) unsigned int*)l, 16, 0, 0);
}

// ---------------- fp32 -> bf16 preconversion (inputs + weights) ----------------
__global__ __launch_bounds__(256)
void cvt_all(const float* __restrict__ q, const float* __restrict__ k,
             const float* __restrict__ v, const float* __restrict__ wq,
             const float* __restrict__ wk, const float* __restrict__ wv,
             const float* __restrict__ wo,
             short* dq, short* dk, short* dv, short* dwq, short* dwk,
             short* dwv, short* dwo) {
    size_t c = (size_t)blockIdx.x * 256 + threadIdx.x;   // 8-elem chunk id
    const float* s; short* d; size_t off;
    if (c < 524288)        { s = q;  d = dq;  off = c; }
    else if (c < 1048576)  { s = k;  d = dk;  off = c - 524288; }
    else if (c < 1572864)  { s = v;  d = dv;  off = c - 1048576; }
    else if (c < 1703936)  { s = wq; d = dwq; off = c - 1572864; }
    else if (c < 1712128)  { s = wk; d = dwk; off = c - 1703936; }
    else if (c < 1720320)  { s = wv; d = dwv; off = c - 1712128; }
    else                   { s = wo; d = dwo; off = c - 1720320; }
    const f32x4* sp = (const f32x4*)(s + off * 8);
    f32x4 a = sp[0], b = sp[1];
    short8 o;
    o[0] = f2bf(a[0]); o[1] = f2bf(a[1]); o[2] = f2bf(a[2]); o[3] = f2bf(a[3]);
    o[4] = f2bf(b[0]); o[5] = f2bf(b[1]); o[6] = f2bf(b[2]); o[7] = f2bf(b[3]);
    *(short8*)(d + off * 8) = o;
}

// ---------------- bf16 MFMA GEMM: C = (A @ W^T + bias) * scale ----------------
template<int BM, int BN, int OUT_MODE>
__device__ __forceinline__ void gemm_body(
    const short* __restrict__ A, const short* __restrict__ Wb,
    const float* __restrict__ bias, void* __restrict__ Cv,
    int bx, int by, int M, int N, int K, float out_scale, char* lds)
{
    constexpr int NI = BM / 32, NJ = BN / 32;
    constexpr int AISS = BM / 32, WISS = BN / 32;
    char* As = lds;                       // [2][BM*128]
    char* Ws = lds + 2 * BM * 128;        // [2][BN*128]
    const int t = threadIdx.x, lane = t & 63, w = t >> 6;
    const int wr = w >> 1, wc = w & 1, r15 = lane & 15, g = lane >> 4;
    const int m0 = by * BM, n0 = bx * BN;
    const size_t Kb2 = (size_t)K * 2;

    int aR[AISS > WISS ? AISS : WISS], aC[AISS > WISS ? AISS : WISS];
#pragma unroll
    for (int i = 0; i < (AISS > WISS ? AISS : WISS); i++) {
        int l = i * 4096 + t * 16;
        aR[i] = l >> 7;
        aC[i] = (l & 127) ^ (((l >> 7) & 7) << 4);
    }

    f32x4 acc[NI][NJ];
#pragma unroll
    for (int i = 0; i < NI; i++)
#pragma unroll
        for (int j = 0; j < NJ; j++) acc[i][j] = (f32x4){0.f, 0.f, 0.f, 0.f};

    const int nk = K / 64;
    auto stage = [&](int kt, int buf) {
        size_t kb = (size_t)kt * 128;
#pragma unroll
        for (int i = 0; i < AISS; i++)
            load_lds16((const char*)A + (size_t)(m0 + aR[i]) * Kb2 + kb + aC[i],
                       As + buf * (BM * 128) + i * 4096 + (w << 10));
#pragma unroll
        for (int i = 0; i < WISS; i++)
            load_lds16((const char*)Wb + (size_t)(n0 + aR[i]) * Kb2 + kb + aC[i],
                       Ws + buf * (BN * 128) + i * 4096 + (w << 10));
    };

    stage(0, 0);
    __syncthreads();
    int cur = 0;
    for (int kt = 0; kt < nk; kt++) {
        if (kt + 1 < nk) stage(kt + 1, cur ^ 1);
        const char* Ab = As + cur * (BM * 128);
        const char* Wbs = Ws + cur * (BN * 128);
#pragma unroll
        for (int kc = 0; kc < 2; kc++) {
            short8 af[NI], bw[NJ];
#pragma unroll
            for (int i = 0; i < NI; i++) {
                int r = wr * (16 * NI) + i * 16 + r15;
                af[i] = *(const short8*)(Ab + r * 128 + ((kc * 64 + g * 16) ^ ((r & 7) << 4)));
            }
#pragma unroll
            for (int j = 0; j < NJ; j++) {
                int r = wc * (16 * NJ) + j * 16 + r15;
                bw[j] = *(const short8*)(Wbs + r * 128 + ((kc * 64 + g * 16) ^ ((r & 7) << 4)));
            }
#pragma unroll
            for (int i = 0; i < NI; i++)
#pragma unroll
                for (int j = 0; j < NJ; j++)
                    acc[i][j] = mfma16(af[i], bw[j], acc[i][j]);
        }
        __syncthreads();
        cur ^= 1;
    }

#pragma unroll
    for (int i = 0; i < NI; i++) {
#pragma unroll
        for (int j = 0; j < NJ; j++) {
            int ncol = n0 + wc * (16 * NJ) + j * 16 + r15;
            float bv = bias[ncol];
#pragma unroll
            for (int reg = 0; reg < 4; reg++) {
                int mrow = m0 + wr * (16 * NI) + i * 16 + g * 4 + reg;
                float val = (acc[i][j][reg] + bv) * out_scale;
                if (OUT_MODE == 0) {
                    __builtin_nontemporal_store(val, (float*)Cv + (size_t)mrow * N + ncol);
                } else if (OUT_MODE == 1) {
                    ((short*)Cv)[(size_t)mrow * N + ncol] = f2bf(val);
                } else {
                    ((short*)Cv)[((((size_t)(mrow >> 11)) * 64 + ncol) << 11) +
                                 (mrow & 2047)] = f2bf(val);
                }
            }
        }
    }
}

__global__ __launch_bounds__(256)
void qkv_proj(const short* __restrict__ qin, const short* __restrict__ kin,
              const short* __restrict__ vin, const short* __restrict__ wqb,
              const short* __restrict__ wkb, const short* __restrict__ wvb,
              const float* __restrict__ bq, const float* __restrict__ bk,
              const float* __restrict__ bv,
              short* Qb, short* Kb, short* Vtb) {
    __shared__ char lds[49152];
    int bid = blockIdx.x;
    if (bid < 512)
        gemm_body<64, 128, 1>(qin, wqb, bq, Qb, bid & 7, bid >> 3,
                              4096, 1024, 1024, 0.18033688011112f, lds); // (1/8)*log2(e)
    else if (bid < 576)
        gemm_body<64, 64, 1>(kin, wkb, bk, Kb, 0, bid - 512,
                             4096, 64, 1024, 1.0f, lds);
    else
        gemm_body<64, 64, 2>(vin, wvb, bv, Vtb, 0, bid - 576,
                             4096, 64, 1024, 1.0f, lds);
}

__global__ __launch_bounds__(256)
void o_proj(const short* __restrict__ ctxb, const short* __restrict__ wob,
            const float* __restrict__ bo, float* __restrict__ out) {
    __shared__ char lds[49152];
    gemm_body<64, 128, 0>(ctxb, wob, bo, out, blockIdx.x & 7, blockIdx.x >> 3,
                          4096, 1024, 1024, 1.0f, lds);
}

// ---------------- Fused MQA attention v5: 64-q blocks, 2 waves, LDS dbuf ----------------
// Block = (b, h, 64-q tile), 2 waves x 32 q-rows. Q pre-scaled by log2e/8, exp2.
// 1024 blocks -> 4 blocks/CU; independent blocks dephase pass1/pass2 so the
// attn write stream stays busy while other blocks compute.
__global__ __launch_bounds__(128)
void mqa_attn5(const short* __restrict__ Qb,   // [B*S][1024] bf16 (pre-scaled)
               const short* __restrict__ Kb,   // [B*S][64]  bf16
               const short* __restrict__ Vtb,  // [B][64][S] bf16
               float* __restrict__ attn,       // [B][H][S][S] fp32
               short* __restrict__ ctxb)       // [B*S][1024] bf16
{
    __shared__ short KB2[2][4096];   // 64x64 bf16 tile per buffer, swizzled
    __shared__ short VB2[2][4096];
    __shared__ short Ps[4096];       // 64 rows x 128B

    const int t = threadIdx.x, lane = t & 63, w = t >> 6;   // w in {0,1}
    const int l31 = lane & 31, h5 = lane >> 5;
    const int bid = blockIdx.x;
    const int qt = bid & 31, h = (bid >> 5) & 15, b = bid >> 9;
    const int q0 = qt * 64;
    const int wq = w * 32;

    // Q A-fragments (32x32x16: lane row = l31, k = kc*16 + h5*8 + j)
    short8 aq[4];
    {
        const char* qbase = (const char*)(Qb +
            (size_t)(b * S_ + q0 + wq + l31) * D_MODEL + h * 64);
#pragma unroll
        for (int kc = 0; kc < 4; kc++)
            aq[kc] = *(const short8*)(qbase + kc * 32 + h5 * 16);
    }

    // staging geometry: tile = 8192B, 128 threads x 16B x 4 issues.
    // linear dest l -> source byte l ^ ((row&7)<<4) (within-row XOR swizzle).
    int koA[4], vcR[4];
    const char* vrowp[4];
#pragma unroll
    for (int i = 0; i < 4; i++) {
        int l = i * 2048 + t * 16;
        int row = l >> 7;
        koA[i] = l ^ ((row & 7) << 4);
        int vc = (l & 127) ^ ((row & 7) << 4);
        vrowp[i] = (const char*)(Vtb + (((size_t)(b * 64 + row)) << 11)) + vc;
    }
    const char* ktile0 = (const char*)(Kb + (size_t)b * S_ * 64);

#define STAGE_K(kti, buf) {                                                    \
        const char* kb_ = ktile0 + (size_t)(kti) * 8192;                       \
        load_lds16(kb_ + koA[0], (char*)KB2 + (buf) * 8192 + 0 * 2048 + (w << 10)); \
        load_lds16(kb_ + koA[1], (char*)KB2 + (buf) * 8192 + 1 * 2048 + (w << 10)); \
        load_lds16(kb_ + koA[2], (char*)KB2 + (buf) * 8192 + 2 * 2048 + (w << 10)); \
        load_lds16(kb_ + koA[3], (char*)KB2 + (buf) * 8192 + 3 * 2048 + (w << 10)); }
#define STAGE_V(kti, buf) {                                                    \
        load_lds16(vrowp[0] + (size_t)(kti) * 128, (char*)VB2 + (buf) * 8192 + 0 * 2048 + (w << 10)); \
        load_lds16(vrowp[1] + (size_t)(kti) * 128, (char*)VB2 + (buf) * 8192 + 1 * 2048 + (w << 10)); \
        load_lds16(vrowp[2] + (size_t)(kti) * 128, (char*)VB2 + (buf) * 8192 + 2 * 2048 + (w << 10)); \
        load_lds16(vrowp[3] + (size_t)(kti) * 128, (char*)VB2 + (buf) * 8192 + 3 * 2048 + (w << 10)); }
#define RD(base, r, cb) (*(const short8*)((const char*)(base) + (r) * 128 + ((cb) ^ (((r) & 7) << 4))))

    // ---- Pass 1: row sums of exp2(s) ----
    float lsum[16];
#pragma unroll
    for (int reg = 0; reg < 16; reg++) lsum[reg] = 0.f;

    int cur = 0;
    STAGE_K(0, 0);
    __syncthreads();
    for (int kti = 0; kti < 32; kti++) {
        if (kti + 1 < 32) STAGE_K(kti + 1, cur ^ 1);
        f32x16 s0 = zero16(), s1 = zero16();
#pragma unroll
        for (int kc = 0; kc < 4; kc++) {
            s0 = mfma32(aq[kc], RD(KB2[cur], l31, kc * 32 + h5 * 16), s0);
            s1 = mfma32(aq[kc], RD(KB2[cur], 32 + l31, kc * 32 + h5 * 16), s1);
        }
#pragma unroll
        for (int reg = 0; reg < 16; reg++)
            lsum[reg] += exp2f(s0[reg]) + exp2f(s1[reg]);
        __syncthreads();
        cur ^= 1;
    }

    float inv[16];
#pragma unroll
    for (int reg = 0; reg < 16; reg++) {
        float v = lsum[reg];
        v += __shfl_xor(v, 1); v += __shfl_xor(v, 2);
        v += __shfl_xor(v, 4); v += __shfl_xor(v, 8); v += __shfl_xor(v, 16);
        inv[reg] = 1.f / v;
    }

    // ---- Pass 2: recompute, nt-store attn, accumulate PV ----
    f32x16 ctxA = zero16(), ctxB = zero16();
    float* attn_base = attn +
        (((size_t)((b * 16 + h) * 2048 + q0 + wq + 4 * h5)) << 11) + l31;

    cur = 0;
    STAGE_K(0, 0);
    STAGE_V(0, 0);
    __syncthreads();
    for (int kti = 0; kti < 32; kti++) {
        if (kti + 1 < 32) { STAGE_K(kti + 1, cur ^ 1); STAGE_V(kti + 1, cur ^ 1); }
        f32x16 s0 = zero16(), s1 = zero16();
#pragma unroll
        for (int kc = 0; kc < 4; kc++) {
            s0 = mfma32(aq[kc], RD(KB2[cur], l31, kc * 32 + h5 * 16), s0);
            s1 = mfma32(aq[kc], RD(KB2[cur], 32 + l31, kc * 32 + h5 * 16), s1);
        }
        float* arowptr = attn_base + (size_t)kti * 64;
#pragma unroll
        for (int reg = 0; reg < 16; reg++) {
            const int rloc = (reg & 3) + 8 * (reg >> 2);
            const int rps = wq + rloc + 4 * h5;
            float p0 = exp2f(s0[reg]) * inv[reg];
            __builtin_nontemporal_store(p0, arowptr + ((size_t)rloc << 11));
            *(short*)((char*)Ps + rps * 128 + ((l31 * 2) ^ ((rps & 7) << 4))) = f2bf(p0);
            float p1 = exp2f(s1[reg]) * inv[reg];
            __builtin_nontemporal_store(p1, arowptr + ((size_t)rloc << 11) + 32);
            *(short*)((char*)Ps + rps * 128 + ((64 + l31 * 2) ^ ((rps & 7) << 4))) = f2bf(p1);
        }
        // PV (same-wave DS order: Ps rows wq..wq+31 written above by this wave)
        short8 ap[4];
#pragma unroll
        for (int kc = 0; kc < 4; kc++)
            ap[kc] = RD(Ps, wq + l31, kc * 32 + h5 * 16);
#pragma unroll
        for (int kc = 0; kc < 4; kc++) {
            ctxA = mfma32(ap[kc], RD(VB2[cur], l31, kc * 32 + h5 * 16), ctxA);
            ctxB = mfma32(ap[kc], RD(VB2[cur], 32 + l31, kc * 32 + h5 * 16), ctxB);
        }
        __syncthreads();
        cur ^= 1;
    }

    const int tokbase = b * 2048 + q0 + wq + 4 * h5;
#pragma unroll
    for (int reg = 0; reg < 16; reg++) {
        const int rloc = (reg & 3) + 8 * (reg >> 2);
        size_t base = (size_t)(tokbase + rloc) * D_MODEL + h * 64 + l31;
        ctxb[base]      = f2bf(ctxA[reg]);
        ctxb[base + 32] = f2bf(ctxB[reg]);
    }
#undef STAGE_K
#undef STAGE_V
#undef RD
}

extern "C" void kernel_launch(void* const* d_in, const int* in_sizes, int n_in,
                              void* d_out, int out_size, void* d_ws, size_t ws_size,
                              hipStream_t stream) {
    const float* query = (const float*)d_in[0];
    const float* key   = (const float*)d_in[1];
    const float* value = (const float*)d_in[2];
    const float* Wq_w  = (const float*)d_in[3];
    const float* Wq_b  = (const float*)d_in[4];
    const float* Wk_w  = (const float*)d_in[5];
    const float* Wk_b  = (const float*)d_in[6];
    const float* Wv_w  = (const float*)d_in[7];
    const float* Wv_b  = (const float*)d_in[8];
    const float* Wo_w  = (const float*)d_in[9];
    const float* Wo_b  = (const float*)d_in[10];

    short* ws   = (short*)d_ws;
    short* qin  = ws;
    short* kin  = qin  + (size_t)4194304;
    short* vin  = kin  + (size_t)4194304;
    short* wqb  = vin  + (size_t)4194304;
    short* wkb  = wqb  + (size_t)1048576;
    short* wvb  = wkb  + (size_t)65536;
    short* wob  = wvb  + (size_t)65536;
    short* Qb   = wob  + (size_t)1048576;
    short* Kb   = Qb   + (size_t)4194304;
    short* Vtb  = Kb   + (size_t)262144;
    short* ctxb = Vtb  + (size_t)262144;

    float* out  = (float*)d_out;
    float* attn = out + (size_t)4096 * 1024;

    dim3 blk(256);

    cvt_all<<<dim3(7232), blk, 0, stream>>>(query, key, value, Wq_w, Wk_w, Wv_w,
                                            Wo_w, qin, kin, vin, wqb, wkb, wvb, wob);
    qkv_proj<<<dim3(640), blk, 0, stream>>>(qin, kin, vin, wqb, wkb, wvb,
                                            Wq_b, Wk_b, Wv_b, Qb, Kb, Vtb);
    mqa_attn5<<<dim3(1024), dim3(128), 0, stream>>>(Qb, Kb, Vtb, attn, ctxb);
    o_proj<<<dim3(512), blk, 0, stream>>>(ctxb, wob, Wo_b, out);
}